// Round 3
// baseline (2249.274 us; speedup 1.0000x reference)
//
#include <hip/hip_runtime.h>

// Single-pass stable stream compaction with decoupled lookback.
// y[:count] = x[x>0] (original order), y[count:n] = 0, y[n] = (float)count.
//
// One read of x, one write of y (values at the front via tile prefix, zeros
// at the mirrored tail: tile t writes its zeros at [n - z_incl(t), ...) which
// partitions [count, n)). Tiles claimed by atomic ticket so lookback only
// ever waits on earlier-claimed (hence resident) blocks -> deadlock-free
// under undefined dispatch order. Device-scope acquire/release for flags
// (per-XCD L2s are not coherent).

#define BLOCK 256
#define VPT 16               // contiguous elems per thread
#define CHUNK (BLOCK * VPT)  // 4096
#define FLAG_INV 0u
#define FLAG_AGG 1u
#define FLAG_PRE 2u

__global__ void k_init(unsigned int* __restrict__ states, int numStates) {
    const int i = blockIdx.x * blockDim.x + threadIdx.x;
    if (i < numStates) states[i] = 0u;
}

// exclusive block scan over 256 threads (4 waves); returns exclusive rank,
// sets *blockTotal.
__device__ __forceinline__ int block_scan_excl_256(int val, int* lds, int* blockTotal) {
    const int tid  = threadIdx.x;
    const int lane = tid & 63;
    const int wave = tid >> 6;
    int incl = val;
#pragma unroll
    for (int off = 1; off < 64; off <<= 1) {
        const int y = __shfl_up(incl, off, 64);
        if (lane >= off) incl += y;
    }
    if (lane == 63) lds[wave] = incl;
    __syncthreads();
    if (tid == 0) {
        const int s0 = lds[0], s1 = lds[1], s2 = lds[2], s3 = lds[3];
        lds[4] = 0; lds[5] = s0; lds[6] = s0 + s1; lds[7] = s0 + s1 + s2;
        lds[8] = s0 + s1 + s2 + s3;
    }
    __syncthreads();
    *blockTotal = lds[8];
    return lds[4 + wave] + incl - val;
}

__global__ __launch_bounds__(BLOCK) void k_compact(
        const float* __restrict__ x, int n, float* __restrict__ y,
        float* __restrict__ countOut, int numTiles,
        unsigned int* __restrict__ states, unsigned int* __restrict__ ticket) {
    __shared__ float stage[CHUNK];     // 16 KB
    __shared__ int lds_scan[9];
    __shared__ int lds_bcast[2];       // [0]=tile, [1]=exclusive offset

    const int tid = threadIdx.x;
    if (tid == 0) lds_bcast[0] = (int)atomicAdd(ticket, 1u);
    __syncthreads();
    const int tile = lds_bcast[0];
    if (tile >= numTiles) return;

    const long long base  = (long long)tile * CHUNK;
    const long long tbase = base + tid * VPT;

    float v[VPT];
    if (tbase + VPT <= n) {
#pragma unroll
        for (int k = 0; k < 4; ++k) {
            const float4 f = *reinterpret_cast<const float4*>(x + tbase + 4 * k);
            v[4 * k + 0] = f.x; v[4 * k + 1] = f.y;
            v[4 * k + 2] = f.z; v[4 * k + 3] = f.w;
        }
    } else {
#pragma unroll
        for (int j = 0; j < VPT; ++j)
            v[j] = (tbase + j < n) ? x[tbase + j] : 0.f;
    }

    int c = 0;
#pragma unroll
    for (int j = 0; j < VPT; ++j) c += (v[j] > 0.f);

    int total;
    int r = block_scan_excl_256(c, lds_scan, &total);

    // Publish aggregate (or full prefix for tile 0) ASAP so successors can proceed.
    if (tid == 0) {
        const unsigned int s = (tile == 0)
            ? (((unsigned int)total << 2) | FLAG_PRE)
            : (((unsigned int)total << 2) | FLAG_AGG);
        __hip_atomic_store(&states[tile], s, __ATOMIC_RELEASE, __HIP_MEMORY_SCOPE_AGENT);
    }

    // Stage values into LDS in stable order (thread-major == element order).
#pragma unroll
    for (int j = 0; j < VPT; ++j) {
        if (v[j] > 0.f) stage[r++] = v[j];
    }

    // Wave 0: decoupled lookback.
    if (tid < 64) {
        int offset = 0;
        if (tile > 0) {
            const int lane = tid;
            int t = tile - 1;
            while (true) {
                const int idx = t - lane;
                unsigned int s;
                if (idx >= 0) {
                    do {
                        s = __hip_atomic_load(&states[idx], __ATOMIC_ACQUIRE,
                                              __HIP_MEMORY_SCOPE_AGENT);
                    } while ((s & 3u) == FLAG_INV);
                } else {
                    s = FLAG_PRE;  // virtual tile with prefix 0
                }
                const unsigned long long pm = __ballot((s & 3u) == FLAG_PRE);
                const int firstPrefix = pm ? (__ffsll((long long)pm) - 1) : -1;
                int val = (int)(s >> 2);
                if (firstPrefix >= 0 && lane > firstPrefix) val = 0;
#pragma unroll
                for (int off = 32; off > 0; off >>= 1) val += __shfl_down(val, off, 64);
                offset += __shfl(val, 0, 64);
                if (firstPrefix >= 0) break;
                t -= 64;
            }
        }
        if (tid == 0) {
            lds_bcast[1] = offset;
            if (tile > 0) {
                __hip_atomic_store(&states[tile],
                                   ((unsigned int)(offset + total) << 2) | FLAG_PRE,
                                   __ATOMIC_RELEASE, __HIP_MEMORY_SCOPE_AGENT);
            }
        }
    }
    __syncthreads();
    const int offset = lds_bcast[1];

    // Coalesced value stores.
    for (int j = tid; j < total; j += BLOCK) y[offset + j] = stage[j];

    // Mirrored zero tail: this tile's zeros land at [n - z_incl, n - z_incl_prev).
    const long long tileEnd = (base + CHUNK < (long long)n) ? base + CHUNK : (long long)n;
    const int size = (int)(tileEnd - base);
    const int zCount = size - total;
    const long long zBase = (long long)n - (tileEnd - (long long)(offset + total));
    for (int j = tid; j < zCount; j += BLOCK) y[zBase + j] = 0.f;

    // Last tile knows the global count.
    if (tileEnd == (long long)n && tid == 0) *countOut = (float)(offset + total);
}

extern "C" void kernel_launch(void* const* d_in, const int* in_sizes, int n_in,
                              void* d_out, int out_size, void* d_ws, size_t ws_size,
                              hipStream_t stream) {
    const float* x = (const float*)d_in[0];
    float* y = (float*)d_out;
    const int n = in_sizes[0];

    const int numTiles = (n + CHUNK - 1) / CHUNK;   // 16384 for N=64M
    unsigned int* states = (unsigned int*)d_ws;
    unsigned int* ticket = states + numTiles;

    const int initN = numTiles + 1;
    k_init<<<(initN + 255) / 256, 256, 0, stream>>>(states, initN);
    k_compact<<<numTiles, BLOCK, 0, stream>>>(x, n, y, y + (out_size - 1),
                                              numTiles, states, ticket);
}